// Round 4
// baseline (241.212 us; speedup 1.0000x reference)
//
#include <hip/hip_runtime.h>
#include <hip/hip_bf16.h>
#include <climits>

// Two-kernel split to decouple the per-row latency chain from the write
// stream (R3 fused version stalled at ~72 us vs the 6.6 TB/s fill ceiling):
//   A) probe_kernel: one WAVE per row. 2-step ballot probe finds len (mask is
//      a contiguous valid prefix), lane 0 runs the exact scalar interval math
//      (proven absmax=0.0 in R2/R3) and writes int2{lo,hi} to d_ws.
//   B) emit_kernel: one block per row. Single wave-uniform 8B ws load
//      (scalar load, L2-hot) -> pure float4 write stream, fill-like.

#define BLOCK 256

__device__ __forceinline__ float sigmoid10(float x) {
    return 1.0f / (1.0f + expf(-10.0f * x));  // matches reference numerics
}
__device__ __forceinline__ float fdiff(float p, float tl, float tr) {
    return sigmoid10(p - tl) - sigmoid10(p - tr);
}

__global__ __launch_bounds__(BLOCK) void probe_kernel(
    const float* __restrict__ t, const float* __restrict__ l,
    const float* __restrict__ mask, int2* __restrict__ ws, int B, int Llen) {
    const int row = blockIdx.x * (BLOCK / 64) + (threadIdx.x >> 6);
    const int lane = threadIdx.x & 63;
    if (row >= B) return;

    const float* mrow = mask + (size_t)row * Llen;

    // ---- step 1: coarse probe, stride = ceil(L/64) ----
    const int stride = (Llen + 63) >> 6;       // 64 for L=4096
    const int pos = lane * stride;
    const float m1 = (pos < Llen) ? mrow[pos] : 0.0f;
    const unsigned long long b1 = __ballot(m1 > 0.5f);
    const int z = __popcll(b1);                // prefix mask: lanes 0..z-1 set

    int len = 0;
    if (z > 0) {
        // ---- step 2: exact probe inside the last known-one bucket ----
        const int base = (z - 1) * stride;
        const int p2 = base + 1 + lane;
        const float m2 = (lane < stride && p2 < Llen) ? mrow[p2] : 0.0f;
        const unsigned long long b2 = __ballot(m2 > 0.5f);
        len = base + 1 + __popcll(b2);
    }

    if (lane == 0) {
        int lo = 1, hi = 0;                    // empty interval default
        if (len > 0) {
            // prefix-mask boundary values: left=-1, right=len, sum=len
            const float leftf  = -1.0f;
            const float rightf = (float)len;
            const float sl = 0.5f * (float)len;
            const float tv = t[row], lv = l[row];
            const float leff = (lv <= sl) ? sl : lv;
            float tl0 = tv - leff;
            float t_left = (tl0 >= leftf) ? tl0 : 0.0f;
            if (t_left == 0.0f) t_left = leftf;
            float tr0 = tv + leff;
            float t_right = (tr0 <= rightf) ? tr0 : 0.0f;
            if (t_right == 0.0f) t_right = rightf;

            // analytic sigmoid-difference >= 0.5 interval
            const float c = expf(-10.0f * (t_right - t_left));
            const float b = 1.0f - 3.0f * c;
            const float disc = b * b - 4.0f * c;
            if (b > 0.0f && disc >= 0.0f) {
                const float xp = 0.5f * (b + sqrtf(disc));
                const float p_lo = t_left - 0.1f * logf(xp);
                const float p_hi = (t_left + t_right) - p_lo;
                lo = (int)ceilf(p_lo);
                hi = (int)floorf(p_hi);
                // refine to exact fp32 classification boundaries
                #pragma unroll 1
                for (int k = 0; k < 4 && fdiff((float)(lo - 1), t_left, t_right) >= 0.5f; ++k) --lo;
                #pragma unroll 1
                for (int k = 0; k < 4 && fdiff((float)lo, t_left, t_right) < 0.5f; ++k) ++lo;
                #pragma unroll 1
                for (int k = 0; k < 4 && fdiff((float)(hi + 1), t_left, t_right) >= 0.5f; ++k) ++hi;
                #pragma unroll 1
                for (int k = 0; k < 4 && fdiff((float)hi, t_left, t_right) < 0.5f; ++k) --hi;
            }
            // fold final "* mask": mask[e]=1 iff e < len
            lo = max(lo, 0);
            hi = min(hi, len - 1);
        }
        ws[row] = make_int2(lo, hi);
    }
}

__global__ __launch_bounds__(BLOCK) void emit_kernel(
    const int2* __restrict__ ws, float* __restrict__ out, int Llen) {
    const int row = blockIdx.x;
    const int2 bnd = ws[row];                  // wave-uniform -> scalar load
    const int lo = bnd.x, hi = bnd.y;

    float4* orow = (float4*)(out + (size_t)row * Llen);
    const int nvec = Llen >> 2;
    for (int j = threadIdx.x; j < nvec; j += BLOCK) {
        const int e = j << 2;
        float4 o;
        o.x = (e     >= lo && e     <= hi) ? 1.0f : 0.0f;
        o.y = (e + 1 >= lo && e + 1 <= hi) ? 1.0f : 0.0f;
        o.z = (e + 2 >= lo && e + 2 <= hi) ? 1.0f : 0.0f;
        o.w = (e + 3 >= lo && e + 3 <= hi) ? 1.0f : 0.0f;
        orow[j] = o;
    }
}

extern "C" void kernel_launch(void* const* d_in, const int* in_sizes, int n_in,
                              void* d_out, int out_size, void* d_ws, size_t ws_size,
                              hipStream_t stream) {
    const float* t    = (const float*)d_in[0];
    const float* l    = (const float*)d_in[1];
    const float* mask = (const float*)d_in[2];
    float* out = (float*)d_out;
    int2* ws = (int2*)d_ws;

    const int B = in_sizes[0];
    const int Llen = in_sizes[2] / B;

    const int rows_per_block = BLOCK / 64;
    probe_kernel<<<(B + rows_per_block - 1) / rows_per_block, BLOCK, 0, stream>>>(
        t, l, mask, ws, B, Llen);
    emit_kernel<<<B, BLOCK, 0, stream>>>(ws, out, Llen);
}

// Round 5
// 228.437 us; speedup vs baseline: 1.0559x; 1.0559x over previous
//
#include <hip/hip_runtime.h>
#include <hip/hip_bf16.h>
#include <climits>

// Persistent-wave kernel. Evidence R1-R4: four structurally different
// kernels (85/84/72/84 us) all shared grid=8192 tiny blocks while the
// harness fill moves 4x the bytes in 80 us -> block launch/drain bound
// (~9 ns/block). Fix: 1024 blocks x 256 threads = 4096 waves, each WAVE
// autonomously handles 2 rows (no LDS, no __syncthreads):
//   - 2-step ballot probe finds len (mask is a contiguous valid prefix)
//   - all lanes redundantly compute the uniform reference scalar math
//     (where()/==0 quirks preserved; proven absmax=0.0 since R2)
//   - boundary refinement PARALLEL: lanes 0-23 evaluate fdiff at lo-window
//     candidates, lanes 24-47 at hi-window; one ballot -> exact fp32
//     boundaries (replaces up to 16 serial fdiff calls)
//   - emit: 16 wave-wide float4 stores (1 KiB per instruction)

#define BLOCK 256
#define WPB (BLOCK / 64)

__device__ __forceinline__ float sigmoid10(float x) {
    return 1.0f / (1.0f + expf(-10.0f * x));  // matches reference numerics
}
__device__ __forceinline__ float fdiff(float p, float tl, float tr) {
    return sigmoid10(p - tl) - sigmoid10(p - tr);
}

__global__ __launch_bounds__(BLOCK) void crop_kernel(
    const float* __restrict__ t, const float* __restrict__ l,
    const float* __restrict__ mask, float* __restrict__ out,
    int B, int Llen, int total_waves) {
    const int lane = threadIdx.x & 63;
    const int wave0 = blockIdx.x * WPB + (threadIdx.x >> 6);

    for (int row = wave0; row < B; row += total_waves) {
        const float* mrow = mask + (size_t)row * Llen;

        // ---- probe: 2-step ballot search for prefix length ----
        const int stride = (Llen + 63) >> 6;       // 64 for L=4096
        const int pos = lane * stride;
        const float m1 = (pos < Llen) ? mrow[pos] : 0.0f;
        const unsigned long long b1 = __ballot(m1 > 0.5f);
        const int z = __popcll(b1);                // wave-uniform

        int len = 0;
        if (z > 0) {
            const int base = (z - 1) * stride;     // last known-one position
            const int p2 = base + 1 + lane;
            const float m2 = (lane < stride && p2 < Llen) ? mrow[p2] : 0.0f;
            const unsigned long long b2 = __ballot(m2 > 0.5f);
            len = base + 1 + __popcll(b2);
        }

        int lo = 1, hi = 0;                        // empty-interval default
        if (len > 0) {
            // uniform scalar math, redundantly on all lanes (broadcast loads)
            const float leftf  = -1.0f;            // argmax(prefix)=0 -> -1
            const float rightf = (float)len;       // L - argmax(rev) = len
            const float sl = 0.5f * (float)len;    // sum/2
            const float tv = t[row], lv = l[row];
            const float leff = (lv <= sl) ? sl : lv;
            float tl0 = tv - leff;
            float t_left = (tl0 >= leftf) ? tl0 : 0.0f;
            if (t_left == 0.0f) t_left = leftf;
            float tr0 = tv + leff;
            float t_right = (tr0 <= rightf) ? tr0 : 0.0f;
            if (t_right == 0.0f) t_right = rightf;

            // analytic sigmoid-difference >= 0.5 interval:
            // x=exp(-10(p-tl)); x^2-(1-3c)x+c<=0, c=exp(-10(tr-tl))
            const float c = expf(-10.0f * (t_right - t_left));
            const float b = 1.0f - 3.0f * c;
            const float disc = b * b - 4.0f * c;
            if (b > 0.0f && disc >= 0.0f) {        // uniform branch
                const float xp = 0.5f * (b + sqrtf(disc));
                const float p_lo = t_left - 0.1f * logf(xp);
                const float p_hi = (t_left + t_right) - p_lo;
                const int lo0 = (int)ceilf(p_lo);
                const int hi0 = (int)floorf(p_hi);
                // parallel exact-fp32 boundary refinement (one ballot):
                // analytic estimate is within ~1 of truth; +-8 window ample
                int cand;
                if (lane < 24)      cand = lo0 - 8 + lane;
                else if (lane < 48) cand = hi0 - 8 + (lane - 24);
                else                cand = lo0;    // don't care
                const bool ok = fdiff((float)cand, t_left, t_right) >= 0.5f;
                const unsigned long long bm = __ballot(ok);
                const unsigned int mlo = (unsigned int)(bm & 0xFFFFFFull);
                const unsigned int mhi = (unsigned int)((bm >> 24) & 0xFFFFFFull);
                // lo = first candidate with f>=0.5 ; hi = last with f>=0.5
                lo = mlo ? (lo0 - 8 + (__ffs(mlo) - 1)) : (lo0 + 16);
                hi = mhi ? (hi0 - 8 + (31 - __clz(mhi))) : (hi0 - 9);
            }
            // fold final "* mask": mask[e]=1 iff e < len
            lo = max(lo, 0);
            hi = min(hi, len - 1);
        }

        // ---- emit: pure wave-wide write stream ----
        float4* orow = (float4*)(out + (size_t)row * Llen);
        const int nvec = Llen >> 2;
        for (int j = lane; j < nvec; j += 64) {
            const int e = j << 2;
            float4 o;
            o.x = (e     >= lo && e     <= hi) ? 1.0f : 0.0f;
            o.y = (e + 1 >= lo && e + 1 <= hi) ? 1.0f : 0.0f;
            o.z = (e + 2 >= lo && e + 2 <= hi) ? 1.0f : 0.0f;
            o.w = (e + 3 >= lo && e + 3 <= hi) ? 1.0f : 0.0f;
            orow[j] = o;
        }
    }
}

extern "C" void kernel_launch(void* const* d_in, const int* in_sizes, int n_in,
                              void* d_out, int out_size, void* d_ws, size_t ws_size,
                              hipStream_t stream) {
    const float* t    = (const float*)d_in[0];
    const float* l    = (const float*)d_in[1];
    const float* mask = (const float*)d_in[2];
    float* out = (float*)d_out;

    const int B = in_sizes[0];
    const int Llen = in_sizes[2] / B;

    const int blocks = 1024;                 // 4 blocks/CU, 16 waves/CU
    const int total_waves = blocks * WPB;    // 4096 -> 2 rows per wave
    crop_kernel<<<blocks, BLOCK, 0, stream>>>(t, l, mask, out, B, Llen, total_waves);
}

// Round 6
// 228.082 us; speedup vs baseline: 1.0576x; 1.0016x over previous
//
#include <hip/hip_runtime.h>
#include <hip/hip_bf16.h>
#include <climits>

// Phase-separated persistent kernel. Evidence R1-R5: every variant that
// interleaves dependent scattered reads with the 134 MB write stream lands
// at ~71 us (1.9 TB/s) while the harness fill proves 6.6 TB/s. Mechanism:
// CDNA's single in-order vmcnt -> s_waitcnt for each probe ballot drains the
// store queue, and probe reads queue behind the write backlog (read
// starvation). Fix: each wave owns RPW contiguous rows; PHASE 1 does ALL
// reads (batched probe1 loads, per-row ballot -> probe2 -> interval math,
// bounds in registers); __syncthreads(); PHASE 2 is a pure register-fed
// store stream with no loads at all.

#define BLOCK 256
#define WPB   (BLOCK / 64)
#define RPW   4   // rows per wave; grid sized so waves*RPW >= B

__device__ __forceinline__ float sigmoid10(float x) {
    return 1.0f / (1.0f + expf(-10.0f * x));  // matches reference numerics
}
__device__ __forceinline__ float fdiff(float p, float tl, float tr) {
    return sigmoid10(p - tl) - sigmoid10(p - tr);
}

__global__ __launch_bounds__(BLOCK) void crop_kernel(
    const float* __restrict__ t, const float* __restrict__ l,
    const float* __restrict__ mask, float* __restrict__ out,
    int B, int Llen) {
    const int lane = threadIdx.x & 63;
    const int wave = blockIdx.x * WPB + (threadIdx.x >> 6);
    const int row0 = wave * RPW;
    const int stride = (Llen + 63) >> 6;       // 64 for L=4096

    int lo_r[RPW], hi_r[RPW];

    // ================= PHASE 1: reads only =================
    // batch the independent probe1 loads (compiler issues all before use)
    float m1[RPW];
    #pragma unroll
    for (int r = 0; r < RPW; ++r) {
        const int row = row0 + r;
        const int pos = lane * stride;
        m1[r] = (row < B && pos < Llen) ? mask[(size_t)row * Llen + pos] : 0.0f;
    }

    #pragma unroll
    for (int r = 0; r < RPW; ++r) {
        const int row = row0 + r;
        int lo = 1, hi = 0;                    // empty-interval default
        if (row < B) {
            const float* mrow = mask + (size_t)row * Llen;
            const unsigned long long b1 = __ballot(m1[r] > 0.5f);
            const int z = __popcll(b1);        // prefix mask: lanes 0..z-1 set
            int len = 0;
            if (z > 0) {
                const int base = (z - 1) * stride;
                const int p2 = base + 1 + lane;
                const float m2 = (lane < stride && p2 < Llen) ? mrow[p2] : 0.0f;
                const unsigned long long b2 = __ballot(m2 > 0.5f);
                len = base + 1 + __popcll(b2);
            }
            if (len > 0) {
                // reference scalar path (uniform on all lanes; absmax=0 since R2)
                const float leftf  = -1.0f;    // argmax(prefix)=0 -> -1
                const float rightf = (float)len;
                const float sl = 0.5f * (float)len;
                const float tv = t[row], lv = l[row];
                const float leff = (lv <= sl) ? sl : lv;
                float tl0 = tv - leff;
                float t_left = (tl0 >= leftf) ? tl0 : 0.0f;
                if (t_left == 0.0f) t_left = leftf;
                float tr0 = tv + leff;
                float t_right = (tr0 <= rightf) ? tr0 : 0.0f;
                if (t_right == 0.0f) t_right = rightf;

                // analytic sigmoid-difference >= 0.5 interval
                const float c = expf(-10.0f * (t_right - t_left));
                const float b = 1.0f - 3.0f * c;
                const float disc = b * b - 4.0f * c;
                if (b > 0.0f && disc >= 0.0f) { // uniform branch
                    const float xp = 0.5f * (b + sqrtf(disc));
                    const float p_lo = t_left - 0.1f * logf(xp);
                    const float p_hi = (t_left + t_right) - p_lo;
                    const int lo0 = (int)ceilf(p_lo);
                    const int hi0 = (int)floorf(p_hi);
                    // parallel exact-fp32 boundary refinement, one ballot
                    int cand;
                    if (lane < 24)      cand = lo0 - 8 + lane;
                    else if (lane < 48) cand = hi0 - 8 + (lane - 24);
                    else                cand = lo0;
                    const bool ok = fdiff((float)cand, t_left, t_right) >= 0.5f;
                    const unsigned long long bm = __ballot(ok);
                    const unsigned int mlo = (unsigned int)(bm & 0xFFFFFFull);
                    const unsigned int mhi = (unsigned int)((bm >> 24) & 0xFFFFFFull);
                    lo = mlo ? (lo0 - 8 + (__ffs(mlo) - 1)) : (lo0 + 16);
                    hi = mhi ? (hi0 - 8 + (31 - __clz(mhi))) : (hi0 - 9);
                }
                lo = max(lo, 0);               // fold "* mask" (prefix)
                hi = min(hi, len - 1);
            }
        }
        lo_r[r] = lo;
        hi_r[r] = hi;
    }

    __syncthreads();   // phase separation: all block reads done before stores

    // ================= PHASE 2: pure store stream =================
    const int nvec = Llen >> 2;
    #pragma unroll
    for (int r = 0; r < RPW; ++r) {
        const int row = row0 + r;
        if (row >= B) continue;
        const int lo = lo_r[r], hi = hi_r[r];
        float4* orow = (float4*)(out + (size_t)row * Llen);
        for (int j = lane; j < nvec; j += 64) {
            const int e = j << 2;
            float4 o;
            o.x = (e     >= lo && e     <= hi) ? 1.0f : 0.0f;
            o.y = (e + 1 >= lo && e + 1 <= hi) ? 1.0f : 0.0f;
            o.z = (e + 2 >= lo && e + 2 <= hi) ? 1.0f : 0.0f;
            o.w = (e + 3 >= lo && e + 3 <= hi) ? 1.0f : 0.0f;
            orow[j] = o;
        }
    }
}

extern "C" void kernel_launch(void* const* d_in, const int* in_sizes, int n_in,
                              void* d_out, int out_size, void* d_ws, size_t ws_size,
                              hipStream_t stream) {
    const float* t    = (const float*)d_in[0];
    const float* l    = (const float*)d_in[1];
    const float* mask = (const float*)d_in[2];
    float* out = (float*)d_out;

    const int B = in_sizes[0];
    const int Llen = in_sizes[2] / B;

    const int rows_per_block = WPB * RPW;      // 16
    const int blocks = (B + rows_per_block - 1) / rows_per_block;  // 512
    crop_kernel<<<blocks, BLOCK, 0, stream>>>(t, l, mask, out, B, Llen);
}

// Round 7
// 220.146 us; speedup vs baseline: 1.0957x; 1.0361x over previous
//
#include <hip/hip_runtime.h>
#include <hip/hip_bf16.h>
#include <climits>

// R7: discriminate probe-fetch cost vs store-stream cap.
//   A) probe_kernel (32 blocks): each LANE owns one row and binary-searches
//      the prefix length (13 dependent 4B loads = ~1.7 KB of lines per row,
//      vs 8.5 KB for the old 64-lane ballot probe -> FETCH 70 MB -> ~14 MB).
//      Each lane then runs the proven scalar interval math (absmax=0.0 since
//      R2) for its own row and writes int2{lo,hi} to d_ws.
//   B) emit_kernel (1024 persistent blocks, wave-per-row): bounds loaded via
//      readfirstlane-forced UNIFORM address -> s_load (lgkmcnt path, fully
//      decoupled from the store queue's vmcnt), then 16 pure float4 stores
//      per lane per row. As fill-like as a correct kernel can be.

#define BLOCK 256

__device__ __forceinline__ float sigmoid10(float x) {
    return 1.0f / (1.0f + expf(-10.0f * x));  // matches reference numerics
}
__device__ __forceinline__ float fdiff(float p, float tl, float tr) {
    return sigmoid10(p - tl) - sigmoid10(p - tr);
}

__global__ __launch_bounds__(BLOCK) void probe_kernel(
    const float* __restrict__ t, const float* __restrict__ l,
    const float* __restrict__ mask, int2* __restrict__ ws, int B, int Llen) {
    const int row = blockIdx.x * BLOCK + threadIdx.x;
    if (row >= B) return;
    const float* mrow = mask + (size_t)row * Llen;

    // ---- binary search for len = first zero (prefix mask; virtual mask[L]=0)
    int blo = -1, bhi = Llen;          // invariant: mask[blo]==1 (or -1), mask[bhi]==0 (or L)
    #pragma unroll 1
    for (int it = 0; it < 13; ++it) {  // 2^13 >= L+1 for L=4096
        int mid = (blo + bhi) >> 1;
        mid = max(mid, 0);             // guard len==0 corner
        const float v = mrow[mid];
        if (v > 0.5f) blo = mid; else bhi = mid;
    }
    const int len = bhi;

    int lo = 1, hi = 0;                // empty-interval default
    if (len > 0) {
        // reference scalar path (prefix mask: left=-1, right=len, sum=len)
        const float leftf  = -1.0f;
        const float rightf = (float)len;
        const float sl = 0.5f * (float)len;
        const float tv = t[row], lv = l[row];
        const float leff = (lv <= sl) ? sl : lv;
        float tl0 = tv - leff;
        float t_left = (tl0 >= leftf) ? tl0 : 0.0f;
        if (t_left == 0.0f) t_left = leftf;
        float tr0 = tv + leff;
        float t_right = (tr0 <= rightf) ? tr0 : 0.0f;
        if (t_right == 0.0f) t_right = rightf;

        // analytic sigmoid-difference >= 0.5 interval
        const float c = expf(-10.0f * (t_right - t_left));
        const float b = 1.0f - 3.0f * c;
        const float disc = b * b - 4.0f * c;
        if (b > 0.0f && disc >= 0.0f) {
            const float xp = 0.5f * (b + sqrtf(disc));
            const float p_lo = t_left - 0.1f * logf(xp);
            const float p_hi = (t_left + t_right) - p_lo;
            lo = (int)ceilf(p_lo);
            hi = (int)floorf(p_hi);
            // refine to exact fp32 classification boundaries (proven path)
            #pragma unroll 1
            for (int k = 0; k < 4 && fdiff((float)(lo - 1), t_left, t_right) >= 0.5f; ++k) --lo;
            #pragma unroll 1
            for (int k = 0; k < 4 && fdiff((float)lo, t_left, t_right) < 0.5f; ++k) ++lo;
            #pragma unroll 1
            for (int k = 0; k < 4 && fdiff((float)(hi + 1), t_left, t_right) >= 0.5f; ++k) ++hi;
            #pragma unroll 1
            for (int k = 0; k < 4 && fdiff((float)hi, t_left, t_right) < 0.5f; ++k) --hi;
        }
        lo = max(lo, 0);               // fold "* mask" (prefix)
        hi = min(hi, len - 1);
    }
    ws[row] = make_int2(lo, hi);
}

__global__ __launch_bounds__(BLOCK) void emit_kernel(
    const int2* __restrict__ ws, float* __restrict__ out,
    int B, int Llen, int total_waves) {
    const int lane = threadIdx.x & 63;
    const int wave0 = blockIdx.x * (BLOCK / 64) + (threadIdx.x >> 6);
    const int nvec = Llen >> 2;

    for (int row = wave0; row < B; row += total_waves) {
        // force a wave-uniform address -> scalar load (lgkmcnt, not vmcnt)
        const int urow = __builtin_amdgcn_readfirstlane(row);
        const int2 bnd = ws[urow];
        const int lo = bnd.x, hi = bnd.y;

        float4* orow = (float4*)(out + (size_t)urow * Llen);
        for (int j = lane; j < nvec; j += 64) {
            const int e = j << 2;
            float4 o;
            o.x = (e     >= lo && e     <= hi) ? 1.0f : 0.0f;
            o.y = (e + 1 >= lo && e + 1 <= hi) ? 1.0f : 0.0f;
            o.z = (e + 2 >= lo && e + 2 <= hi) ? 1.0f : 0.0f;
            o.w = (e + 3 >= lo && e + 3 <= hi) ? 1.0f : 0.0f;
            orow[j] = o;
        }
    }
}

extern "C" void kernel_launch(void* const* d_in, const int* in_sizes, int n_in,
                              void* d_out, int out_size, void* d_ws, size_t ws_size,
                              hipStream_t stream) {
    const float* t    = (const float*)d_in[0];
    const float* l    = (const float*)d_in[1];
    const float* mask = (const float*)d_in[2];
    float* out = (float*)d_out;
    int2* ws = (int2*)d_ws;

    const int B = in_sizes[0];
    const int Llen = in_sizes[2] / B;

    probe_kernel<<<(B + BLOCK - 1) / BLOCK, BLOCK, 0, stream>>>(t, l, mask, ws, B, Llen);

    const int blocks = 1024;                      // persistent, 4 waves/block
    const int total_waves = blocks * (BLOCK / 64);
    emit_kernel<<<blocks, BLOCK, 0, stream>>>(ws, out, B, Llen, total_waves);
}

// Round 8
// 219.561 us; speedup vs baseline: 1.0986x; 1.0027x over previous
//
#include <hip/hip_runtime.h>
#include <hip/hip_bf16.h>
#include <climits>

// R8: emit with FILL-IDENTICAL address pattern.
// Evidence R1-R7: every row-chunked emit (wave-per-row) caps at ~2.4 TB/s
// while rocclr fillBufferAligned sustains 6.6 TB/s on the same buffer in the
// same graph. Last structural difference: fill writes ONE contiguous sliding
// window; row-chunked emits keep ~4096 concurrent 16 KB write streams open
// (DRAM page thrash). Fix: flat grid-stride float4 emit (idx = gtid + k*grid),
// bounds looked up from the 64 KB ws table (L2-hot) and software-prefetched
// one iteration ahead. Probe kernel = R7's proven binary-search (absmax 0.0).

#define BLOCK 256

__device__ __forceinline__ float sigmoid10(float x) {
    return 1.0f / (1.0f + expf(-10.0f * x));  // matches reference numerics
}
__device__ __forceinline__ float fdiff(float p, float tl, float tr) {
    return sigmoid10(p - tl) - sigmoid10(p - tr);
}

__global__ __launch_bounds__(BLOCK) void probe_kernel(
    const float* __restrict__ t, const float* __restrict__ l,
    const float* __restrict__ mask, int2* __restrict__ ws, int B, int Llen) {
    const int row = blockIdx.x * BLOCK + threadIdx.x;
    if (row >= B) return;
    const float* mrow = mask + (size_t)row * Llen;

    // binary search for len = first zero (contiguous valid-prefix mask)
    int blo = -1, bhi = Llen;
    #pragma unroll 1
    for (int it = 0; it < 13; ++it) {  // 2^13 >= L+1 for L=4096
        int mid = (blo + bhi) >> 1;
        mid = max(mid, 0);
        const float v = mrow[mid];
        if (v > 0.5f) blo = mid; else bhi = mid;
    }
    const int len = bhi;

    int lo = 1, hi = 0;                // empty-interval default
    if (len > 0) {
        // reference scalar path (prefix mask: left=-1, right=len, sum=len)
        const float leftf  = -1.0f;
        const float rightf = (float)len;
        const float sl = 0.5f * (float)len;
        const float tv = t[row], lv = l[row];
        const float leff = (lv <= sl) ? sl : lv;
        float tl0 = tv - leff;
        float t_left = (tl0 >= leftf) ? tl0 : 0.0f;
        if (t_left == 0.0f) t_left = leftf;
        float tr0 = tv + leff;
        float t_right = (tr0 <= rightf) ? tr0 : 0.0f;
        if (t_right == 0.0f) t_right = rightf;

        // analytic sigmoid-difference >= 0.5 interval
        const float c = expf(-10.0f * (t_right - t_left));
        const float b = 1.0f - 3.0f * c;
        const float disc = b * b - 4.0f * c;
        if (b > 0.0f && disc >= 0.0f) {
            const float xp = 0.5f * (b + sqrtf(disc));
            const float p_lo = t_left - 0.1f * logf(xp);
            const float p_hi = (t_left + t_right) - p_lo;
            lo = (int)ceilf(p_lo);
            hi = (int)floorf(p_hi);
            // refine to exact fp32 classification boundaries (proven path)
            #pragma unroll 1
            for (int k = 0; k < 4 && fdiff((float)(lo - 1), t_left, t_right) >= 0.5f; ++k) --lo;
            #pragma unroll 1
            for (int k = 0; k < 4 && fdiff((float)lo, t_left, t_right) < 0.5f; ++k) ++lo;
            #pragma unroll 1
            for (int k = 0; k < 4 && fdiff((float)(hi + 1), t_left, t_right) >= 0.5f; ++k) ++hi;
            #pragma unroll 1
            for (int k = 0; k < 4 && fdiff((float)hi, t_left, t_right) < 0.5f; ++k) --hi;
        }
        lo = max(lo, 0);               // fold "* mask" (prefix)
        hi = min(hi, len - 1);
    }
    ws[row] = make_int2(lo, hi);
}

// flat fill-style emit: one contiguous sliding window across the whole output
__global__ __launch_bounds__(BLOCK) void emit_flat_kernel(
    const int2* __restrict__ ws, float4* __restrict__ out,
    int total_v4, int log2_nv4) {
    const int stride = gridDim.x * BLOCK;
    int idx = blockIdx.x * BLOCK + threadIdx.x;
    if (idx >= total_v4) return;

    int2 bnd = ws[idx >> log2_nv4];            // prefetch for first iteration
    while (true) {
        const int nxt = idx + stride;
        int2 bnext;
        if (nxt < total_v4) bnext = ws[nxt >> log2_nv4];  // prefetch next
        const int e = (idx & ((1 << log2_nv4) - 1)) << 2; // col of .x
        float4 o;
        o.x = (e     >= bnd.x && e     <= bnd.y) ? 1.0f : 0.0f;
        o.y = (e + 1 >= bnd.x && e + 1 <= bnd.y) ? 1.0f : 0.0f;
        o.z = (e + 2 >= bnd.x && e + 2 <= bnd.y) ? 1.0f : 0.0f;
        o.w = (e + 3 >= bnd.x && e + 3 <= bnd.y) ? 1.0f : 0.0f;
        out[idx] = o;
        if (nxt >= total_v4) break;
        idx = nxt;
        bnd = bnext;
    }
}

// fallback for non-power-of-two row length (not hit at L=4096)
__global__ __launch_bounds__(BLOCK) void emit_row_kernel(
    const int2* __restrict__ ws, float* __restrict__ out,
    int B, int Llen, int total_waves) {
    const int lane = threadIdx.x & 63;
    const int wave0 = blockIdx.x * (BLOCK / 64) + (threadIdx.x >> 6);
    const int nvec = Llen >> 2;
    for (int row = wave0; row < B; row += total_waves) {
        const int2 bnd = ws[row];
        float4* orow = (float4*)(out + (size_t)row * Llen);
        for (int j = lane; j < nvec; j += 64) {
            const int e = j << 2;
            float4 o;
            o.x = (e     >= bnd.x && e     <= bnd.y) ? 1.0f : 0.0f;
            o.y = (e + 1 >= bnd.x && e + 1 <= bnd.y) ? 1.0f : 0.0f;
            o.z = (e + 2 >= bnd.x && e + 2 <= bnd.y) ? 1.0f : 0.0f;
            o.w = (e + 3 >= bnd.x && e + 3 <= bnd.y) ? 1.0f : 0.0f;
            orow[j] = o;
        }
    }
}

extern "C" void kernel_launch(void* const* d_in, const int* in_sizes, int n_in,
                              void* d_out, int out_size, void* d_ws, size_t ws_size,
                              hipStream_t stream) {
    const float* t    = (const float*)d_in[0];
    const float* l    = (const float*)d_in[1];
    const float* mask = (const float*)d_in[2];
    float* out = (float*)d_out;
    int2* ws = (int2*)d_ws;

    const int B = in_sizes[0];
    const int Llen = in_sizes[2] / B;

    probe_kernel<<<(B + BLOCK - 1) / BLOCK, BLOCK, 0, stream>>>(t, l, mask, ws, B, Llen);

    const int nv4 = Llen >> 2;                     // float4 per row (1024)
    if ((nv4 & (nv4 - 1)) == 0) {
        int lg = 0; while ((1 << lg) < nv4) ++lg;  // log2(nv4) = 10
        const int total_v4 = B * nv4;              // 8.4M
        const int blocks = 2048;                   // 16 full sliding windows
        emit_flat_kernel<<<blocks, BLOCK, 0, stream>>>(ws, (float4*)out, total_v4, lg);
    } else {
        const int blocks = 1024;
        emit_row_kernel<<<blocks, BLOCK, 0, stream>>>(ws, out, B, Llen, blocks * (BLOCK / 64));
    }
}

// Round 10
// 218.261 us; speedup vs baseline: 1.1052x; 1.0060x over previous
//
#include <hip/hip_runtime.h>
#include <hip/hip_bf16.h>
#include <climits>

// R10 = R9 with the compile fix: __builtin_nontemporal_store requires a
// NATIVE vector type (ext_vector_type), not HIP's float4 class. Theory
// unchanged: plain stores write-allocate in the 4 MiB/XCD L2 -> 128 MiB
// stream thrashes it, drains as scattered writebacks (~2.4 TB/s in ALL of
// R1-R8); nt stores bypass L2 alloc and stream at fill's proven 6.6 TB/s.
// Probe kernel unchanged (binary-search, absmax 0.0 since R2).

#define BLOCK 256

typedef float nfloat4 __attribute__((ext_vector_type(4)));  // native vec4

__device__ __forceinline__ float sigmoid10(float x) {
    return 1.0f / (1.0f + expf(-10.0f * x));  // matches reference numerics
}
__device__ __forceinline__ float fdiff(float p, float tl, float tr) {
    return sigmoid10(p - tl) - sigmoid10(p - tr);
}

__global__ __launch_bounds__(BLOCK) void probe_kernel(
    const float* __restrict__ t, const float* __restrict__ l,
    const float* __restrict__ mask, int2* __restrict__ ws, int B, int Llen) {
    const int row = blockIdx.x * BLOCK + threadIdx.x;
    if (row >= B) return;
    const float* mrow = mask + (size_t)row * Llen;

    // binary search for len = first zero (contiguous valid-prefix mask)
    int blo = -1, bhi = Llen;
    #pragma unroll 1
    for (int it = 0; it < 13; ++it) {  // 2^13 >= L+1 for L=4096
        int mid = (blo + bhi) >> 1;
        mid = max(mid, 0);
        const float v = mrow[mid];
        if (v > 0.5f) blo = mid; else bhi = mid;
    }
    const int len = bhi;

    int lo = 1, hi = 0;                // empty-interval default
    if (len > 0) {
        // reference scalar path (prefix mask: left=-1, right=len, sum=len)
        const float leftf  = -1.0f;
        const float rightf = (float)len;
        const float sl = 0.5f * (float)len;
        const float tv = t[row], lv = l[row];
        const float leff = (lv <= sl) ? sl : lv;
        float tl0 = tv - leff;
        float t_left = (tl0 >= leftf) ? tl0 : 0.0f;
        if (t_left == 0.0f) t_left = leftf;
        float tr0 = tv + leff;
        float t_right = (tr0 <= rightf) ? tr0 : 0.0f;
        if (t_right == 0.0f) t_right = rightf;

        // analytic sigmoid-difference >= 0.5 interval
        const float c = expf(-10.0f * (t_right - t_left));
        const float b = 1.0f - 3.0f * c;
        const float disc = b * b - 4.0f * c;
        if (b > 0.0f && disc >= 0.0f) {
            const float xp = 0.5f * (b + sqrtf(disc));
            const float p_lo = t_left - 0.1f * logf(xp);
            const float p_hi = (t_left + t_right) - p_lo;
            lo = (int)ceilf(p_lo);
            hi = (int)floorf(p_hi);
            // refine to exact fp32 classification boundaries (proven path)
            #pragma unroll 1
            for (int k = 0; k < 4 && fdiff((float)(lo - 1), t_left, t_right) >= 0.5f; ++k) --lo;
            #pragma unroll 1
            for (int k = 0; k < 4 && fdiff((float)lo, t_left, t_right) < 0.5f; ++k) ++lo;
            #pragma unroll 1
            for (int k = 0; k < 4 && fdiff((float)(hi + 1), t_left, t_right) >= 0.5f; ++k) ++hi;
            #pragma unroll 1
            for (int k = 0; k < 4 && fdiff((float)hi, t_left, t_right) < 0.5f; ++k) --hi;
        }
        lo = max(lo, 0);               // fold "* mask" (prefix)
        hi = min(hi, len - 1);
    }
    ws[row] = make_int2(lo, hi);
}

// flat fill-style emit, NONTEMPORAL stores (native vec4)
__global__ __launch_bounds__(BLOCK) void emit_flat_kernel(
    const int2* __restrict__ ws, nfloat4* __restrict__ out,
    int total_v4, int log2_nv4) {
    const int stride = gridDim.x * BLOCK;
    int idx = blockIdx.x * BLOCK + threadIdx.x;
    if (idx >= total_v4) return;

    int2 bnd = ws[idx >> log2_nv4];            // prefetch for first iteration
    while (true) {
        const int nxt = idx + stride;
        int2 bnext;
        if (nxt < total_v4) bnext = ws[nxt >> log2_nv4];  // prefetch next
        const int e = (idx & ((1 << log2_nv4) - 1)) << 2; // col of .x
        nfloat4 o;
        o.x = (e     >= bnd.x && e     <= bnd.y) ? 1.0f : 0.0f;
        o.y = (e + 1 >= bnd.x && e + 1 <= bnd.y) ? 1.0f : 0.0f;
        o.z = (e + 2 >= bnd.x && e + 2 <= bnd.y) ? 1.0f : 0.0f;
        o.w = (e + 3 >= bnd.x && e + 3 <= bnd.y) ? 1.0f : 0.0f;
        __builtin_nontemporal_store(o, &out[idx]);   // nt: bypass L2 alloc
        if (nxt >= total_v4) break;
        idx = nxt;
        bnd = bnext;
    }
}

// fallback for non-power-of-two row length (not hit at L=4096)
__global__ __launch_bounds__(BLOCK) void emit_row_kernel(
    const int2* __restrict__ ws, float* __restrict__ out,
    int B, int Llen, int total_waves) {
    const int lane = threadIdx.x & 63;
    const int wave0 = blockIdx.x * (BLOCK / 64) + (threadIdx.x >> 6);
    const int nvec = Llen >> 2;
    for (int row = wave0; row < B; row += total_waves) {
        const int2 bnd = ws[row];
        nfloat4* orow = (nfloat4*)(out + (size_t)row * Llen);
        for (int j = lane; j < nvec; j += 64) {
            const int e = j << 2;
            nfloat4 o;
            o.x = (e     >= bnd.x && e     <= bnd.y) ? 1.0f : 0.0f;
            o.y = (e + 1 >= bnd.x && e + 1 <= bnd.y) ? 1.0f : 0.0f;
            o.z = (e + 2 >= bnd.x && e + 2 <= bnd.y) ? 1.0f : 0.0f;
            o.w = (e + 3 >= bnd.x && e + 3 <= bnd.y) ? 1.0f : 0.0f;
            __builtin_nontemporal_store(o, &orow[j]);
        }
    }
}

extern "C" void kernel_launch(void* const* d_in, const int* in_sizes, int n_in,
                              void* d_out, int out_size, void* d_ws, size_t ws_size,
                              hipStream_t stream) {
    const float* t    = (const float*)d_in[0];
    const float* l    = (const float*)d_in[1];
    const float* mask = (const float*)d_in[2];
    float* out = (float*)d_out;
    int2* ws = (int2*)d_ws;

    const int B = in_sizes[0];
    const int Llen = in_sizes[2] / B;

    probe_kernel<<<(B + BLOCK - 1) / BLOCK, BLOCK, 0, stream>>>(t, l, mask, ws, B, Llen);

    const int nv4 = Llen >> 2;                     // float4 per row (1024)
    if ((nv4 & (nv4 - 1)) == 0) {
        int lg = 0; while ((1 << lg) < nv4) ++lg;  // log2(nv4) = 10
        const int total_v4 = B * nv4;              // 8.4M
        const int blocks = 2048;                   // 16 full sliding windows
        emit_flat_kernel<<<blocks, BLOCK, 0, stream>>>(ws, (nfloat4*)out, total_v4, lg);
    } else {
        const int blocks = 1024;
        emit_row_kernel<<<blocks, BLOCK, 0, stream>>>(ws, out, B, Llen, blocks * (BLOCK / 64));
    }
}